// Round 5
// baseline (621.131 us; speedup 1.0000x reference)
//
#include <hip/hip_runtime.h>
#include <hip/hip_bf16.h>
#include <stdint.h>

#define BQ   8
#define SEQ  2048
#define EMB  512
#define KVB  32
#define HALF 1024   // keys per split-KV block
#define QTILE 128

typedef __attribute__((ext_vector_type(8))) short short8;
typedef __attribute__((ext_vector_type(4))) float floatx4;
typedef __attribute__((ext_vector_type(4))) unsigned short ushort4_t;
typedef __hip_bfloat16 bf16;

__device__ __forceinline__ unsigned short f2bf(float f) {
    union { bf16 h; unsigned short u; } c;
    c.h = __float2bfloat16(f);
    return c.u;
}

// ---------------- fp32 -> bf16 convert (optionally scaled) ----------------
__global__ __launch_bounds__(256) void cvt_f32_to_bf16(
    const float* __restrict__ in, bf16* __restrict__ out, long n4, float scale)
{
    long i = (long)blockIdx.x * 256 + threadIdx.x;
    if (i >= n4) return;
    floatx4 v = *(const floatx4*)(in + i * 4);
    ushort4_t o;
    o.x = f2bf(v.x * scale);
    o.y = f2bf(v.y * scale);
    o.z = f2bf(v.z * scale);
    o.w = f2bf(v.w * scale);
    *(ushort4_t*)((unsigned short*)out + i * 4) = o;
}

// ---------------- mask(bool, stored as int32 OR uint8) -> f32 bias --------
__global__ __launch_bounds__(256) void mask_to_bias(
    const void* __restrict__ mraw, float* __restrict__ bias)
{
    __shared__ int bad;
    int tid = threadIdx.x;
    if (tid == 0) bad = 0;
    __syncthreads();
    const int* mi = (const int*)mraw;
    int local = 0;
    for (int i = tid; i < 4096; i += 256) {
        unsigned v = (unsigned)mi[i];
        if (v > 1u) local = 1;
    }
    if (local) atomicOr(&bad, 1);
    __syncthreads();
    bool as_int = (bad == 0);
    const unsigned char* mb = (const unsigned char*)mraw;
    for (int i = tid; i < BQ * SEQ; i += 256) {
        int mv = as_int ? mi[i] : (int)mb[i];
        bias[i] = mv ? -1e9f : 0.0f;
    }
}

// ---------------- B^T GEMM: C[m][n] = sum_k A[m][k]*Bt[n][k] --------------
enum { EPI_BF16 = 0, EPI_TRANS = 1 };

template <int EPI>
__global__ __launch_bounds__(256) void gemm_bt(
    const bf16* __restrict__ A, const bf16* __restrict__ Bt,
    void* __restrict__ C, int Ncols, int K)
{
    __shared__ __attribute__((aligned(16))) bf16 lA[128 * 32];
    __shared__ __attribute__((aligned(16))) bf16 lB[128 * 32];

    const int tid  = threadIdx.x;
    const int lane = tid & 63;
    const int wv   = tid >> 6;
    const int wr   = wv >> 1, wc = wv & 1;
    const long brow = (long)blockIdx.y * 128;
    const long bcol = (long)blockIdx.x * 128;

    floatx4 acc[4][4];
#pragma unroll
    for (int m = 0; m < 4; m++)
#pragma unroll
        for (int n = 0; n < 4; n++) acc[m][n] = (floatx4)0.0f;

    const int hi  = lane >> 4;
    const int r16 = lane & 15;

    for (int kt = 0; kt < K; kt += 32) {
#pragma unroll
        for (int it = 0; it < 2; ++it) {
            int c = it * 256 + tid;
            const bf16* src = A + (brow + (c >> 2)) * (long)K + kt + (c & 3) * 8;
            __builtin_amdgcn_global_load_lds(
                (const __attribute__((address_space(1))) void*)src,
                (__attribute__((address_space(3))) void*)(&lA[(it * 256 + wv * 64) * 8]),
                16, 0, 0);
        }
#pragma unroll
        for (int it = 0; it < 2; ++it) {
            int c = it * 256 + tid;
            const bf16* src = Bt + (bcol + (c >> 2)) * (long)K + kt + (c & 3) * 8;
            __builtin_amdgcn_global_load_lds(
                (const __attribute__((address_space(1))) void*)src,
                (__attribute__((address_space(3))) void*)(&lB[(it * 256 + wv * 64) * 8]),
                16, 0, 0);
        }
        __syncthreads();

        short8 af[4], bfr[4];
#pragma unroll
        for (int m = 0; m < 4; m++)
            af[m] = *(const short8*)&lA[(wr * 64 + m * 16 + r16) * 32 + hi * 8];
#pragma unroll
        for (int n = 0; n < 4; n++)
            bfr[n] = *(const short8*)&lB[(wc * 64 + n * 16 + r16) * 32 + hi * 8];
#pragma unroll
        for (int m = 0; m < 4; m++)
#pragma unroll
            for (int n = 0; n < 4; n++)
                acc[m][n] = __builtin_amdgcn_mfma_f32_16x16x32_bf16(
                    af[m], bfr[n], acc[m][n], 0, 0, 0);
        __syncthreads();
    }

#pragma unroll
    for (int m = 0; m < 4; m++) {
#pragma unroll
        for (int n = 0; n < 4; n++) {
#pragma unroll
            for (int j = 0; j < 4; j++) {
                long row = brow + wr * 64 + m * 16 + hi * 4 + j;
                long col = bcol + wc * 64 + n * 16 + r16;
                float v = acc[m][n][j];
                if constexpr (EPI == EPI_BF16) {
                    ((bf16*)C)[row * (long)Ncols + col] = __float2bfloat16(v);
                } else { // EPI_TRANS: Vt[b][e][n]
                    long bb = row >> 11, t = row & 2047;
                    ((bf16*)C)[(bb * EMB + col) * SEQ + t] = __float2bfloat16(v);
                }
            }
        }
    }
}

// ---------------- fused flash attention, swapped-S, 8 waves ---------------
// grid 256: bid&7=batch (XCD), (bid>>3)&15=qtile(128 rows), bid>>7=KV half.
// Each wave owns 16 q-rows: S^T = mfma(K, Q) -> lane(hi,r16) holds
// P[q=wv*16+r16][keys 4hi+j / 16+4hi+j]. Softmax fully in-register
// (reduce over hi = 2 shfl_xor). PV at K=32 rate with key-permuted
// operands (pa slots and V frag use same permutation pi(hi,s)).
__global__ __launch_bounds__(512, 2) void flash_attn(
    const bf16* __restrict__ Q, const bf16* __restrict__ K,
    const bf16* __restrict__ Vt, const float* __restrict__ bias,
    float* __restrict__ part, float2* __restrict__ ml)
{
    __shared__ __attribute__((aligned(16))) bf16 Klds[2][KVB * EMB];  // 64KB
    __shared__ float biasLds[HALF];                                    // 4KB

    const int tid  = threadIdx.x;
    const int lane = tid & 63;
    const int wv   = tid >> 6;          // 0..7
    const int r16  = lane & 15, hi = lane >> 4;

    const int bid = blockIdx.x;
    const int b   = bid & 7;            // batch -> XCD
    const int qt  = (bid >> 3) & 15;    // 0..15
    const int h   = bid >> 7;           // KV half
    const long q0  = (long)qt * QTILE;
    const long kv0 = (long)h * HALF;
    const int NT   = HALF / KVB;        // 32

    const bf16* Qb = Q  + (long)b * SEQ * EMB;
    const bf16* Kb = K  + (long)b * SEQ * EMB + kv0 * EMB;
    const bf16* Vb = Vt + (long)b * EMB * SEQ;
    const float* biasb = bias + (long)b * SEQ + kv0;

    if (tid < HALF / 4)
        *(floatx4*)&biasLds[tid * 4] = *(const floatx4*)&biasb[tid * 4];

    // Q fragments (B-operand): q-row q0 + wv*16 + r16, d-slices hi*8 per ks
    short8 qf[16];
    {
        const bf16* qrow = Qb + (q0 + wv * 16 + r16) * EMB;
#pragma unroll
        for (int ks = 0; ks < 16; ks++)
            qf[ks] = *(const short8*)(qrow + ks * 32 + hi * 8);
    }

    floatx4 oacc[32];
#pragma unroll
    for (int nf = 0; nf < 32; nf++) oacc[nf] = (floatx4)0.f;

    float m_r = -3e38f, l_r = 0.f;

    auto stageK = [&](int buf, int t) {
#pragma unroll
        for (int c = 0; c < 4; c++) {
            int row = c * 8 + wv;
            const bf16* src = Kb + ((long)t * KVB + row) * EMB + (lane ^ (row & 7)) * 8;
            __builtin_amdgcn_global_load_lds(
                (const __attribute__((address_space(1))) void*)src,
                (__attribute__((address_space(3))) void*)(&Klds[buf][row * EMB]),
                16, 0, 0);
        }
    };

    stageK(0, 0);
    __syncthreads();

    for (int t = 0; t < NT; t++) {
        const int cur = t & 1;
        if (t + 1 < NT) stageK(cur ^ 1, t + 1);   // overlaps this tile's work

        // ---- S^T = mfma(A=K, B=Q): c0 keys 0..15 (rows r16), c1 keys 16..31
        floatx4 c0 = (floatx4)0.f, c1 = (floatx4)0.f;
        const char* kbase = (const char*)&Klds[cur][0];
        const int rowb0 = r16 * 1024, rowb1 = rowb0 + 16 * 1024;
        const int sw = r16 & 7;
        __builtin_amdgcn_s_setprio(1);
#pragma unroll
        for (int ks = 0; ks < 16; ks++) {
            const int cc = ((ks * 4 + hi) ^ sw) << 4;
            short8 k0 = *(const short8*)(kbase + rowb0 + cc);
            c0 = __builtin_amdgcn_mfma_f32_16x16x32_bf16(k0, qf[ks], c0, 0, 0, 0);
            short8 k1 = *(const short8*)(kbase + rowb1 + cc);
            c1 = __builtin_amdgcn_mfma_f32_16x16x32_bf16(k1, qf[ks], c1, 0, 0, 0);
        }
        __builtin_amdgcn_s_setprio(0);

        // ---- in-register online softmax (lane owns q-row r16) ----
        float s0[4], s1[4];
        float tmax;
        {
#pragma unroll
            for (int j = 0; j < 4; j++) {
                s0[j] = c0[j] + biasLds[t * KVB + hi * 4 + j];
                s1[j] = c1[j] + biasLds[t * KVB + 16 + hi * 4 + j];
            }
            float a = fmaxf(fmaxf(s0[0], s0[1]), fmaxf(s0[2], s0[3]));
            float bmx = fmaxf(fmaxf(s1[0], s1[1]), fmaxf(s1[2], s1[3]));
            tmax = fmaxf(a, bmx);
            tmax = fmaxf(tmax, __shfl_xor(tmax, 16));
            tmax = fmaxf(tmax, __shfl_xor(tmax, 32));
        }
        float sc = 1.0f;
        int resc = 0;
        if (tmax > m_r + 8.0f) {                  // defer-max (T13)
            sc = __expf(m_r - tmax);
            m_r = tmax;
            resc = 1;
        }
        float p0[4], p1[4], rsum = 0.f;
#pragma unroll
        for (int j = 0; j < 4; j++) {
            p0[j] = __expf(s0[j] - m_r);
            p1[j] = __expf(s1[j] - m_r);
            rsum += p0[j] + p1[j];
        }
        rsum += __shfl_xor(rsum, 16);
        rsum += __shfl_xor(rsum, 32);
        l_r = l_r * sc + rsum;

        // pack pa: slots 0..3 = p0, 4..7 = p1 (key permutation pi(hi,s))
        short8 pa;
#pragma unroll
        for (int j = 0; j < 4; j++) {
            pa[j]     = (short)f2bf(p0[j]);
            pa[4 + j] = (short)f2bf(p1[j]);
        }

        if (__any(resc)) {                        // rare O-rescale
#pragma unroll
            for (int j = 0; j < 4; j++) {
                float f = __shfl(sc, hi * 4 + j); // sc of q-row hi*4+j
#pragma unroll
                for (int nf = 0; nf < 32; nf++) oacc[nf][j] *= f;
            }
        }

        // ---- O += P @ V, key-permuted B-frag from global Vt ----
        const bf16* vp = Vb + (long)r16 * SEQ + kv0 + (long)t * KVB + hi * 4;
        __builtin_amdgcn_s_setprio(1);
#pragma unroll
        for (int nf = 0; nf < 32; nf++) {
            ushort4_t va = *(const ushort4_t*)vp;          // keys 4hi..+3
            ushort4_t vb2 = *(const ushort4_t*)(vp + 16);  // keys 16+4hi..+3
            short8 bfrag;
            bfrag[0] = (short)va.x;  bfrag[1] = (short)va.y;
            bfrag[2] = (short)va.z;  bfrag[3] = (short)va.w;
            bfrag[4] = (short)vb2.x; bfrag[5] = (short)vb2.y;
            bfrag[6] = (short)vb2.z; bfrag[7] = (short)vb2.w;
            oacc[nf] = __builtin_amdgcn_mfma_f32_16x16x32_bf16(
                pa, bfrag, oacc[nf], 0, 0, 0);
            vp += 16 * SEQ;
        }
        __builtin_amdgcn_s_setprio(0);

        __syncthreads();   // all waves done with Klds[cur]; staging drained
    }

    // ---- epilogue: unnormalized O partial + (m,l) per q-row ----
    float* pb = part + (long)bid * QTILE * EMB;
#pragma unroll
    for (int j = 0; j < 4; j++) {
        long row = wv * 16 + hi * 4 + j;
#pragma unroll
        for (int nf = 0; nf < 32; nf++)
            pb[row * EMB + nf * 16 + r16] = oacc[nf][j];
    }
    if (hi == 0)
        ml[(long)bid * QTILE + wv * 16 + r16] = make_float2(m_r, l_r);
}

// ---------------- combine the two KV halves -------------------------------
__global__ __launch_bounds__(128) void combine_halves(
    const float* __restrict__ part, const float2* __restrict__ ml,
    float* __restrict__ out)
{
    const int r  = blockIdx.x;              // 0..16383 global q-row
    const int b  = r >> 11;
    const int rb = r & 2047;
    const int qt = rb >> 7;
    const int rr = rb & 127;
    const int s0 = qt * 8 + b;              // slot of half 0
    const int s1 = s0 + 128;

    float2 ml0 = ml[(long)s0 * QTILE + rr];
    float2 ml1 = ml[(long)s1 * QTILE + rr];
    float M  = fmaxf(ml0.x, ml1.x);
    float w0 = __expf(ml0.x - M), w1 = __expf(ml1.x - M);
    float inv = 1.0f / (w0 * ml0.y + w1 * ml1.y);
    w0 *= inv; w1 *= inv;

    const floatx4* p0 = (const floatx4*)(part + ((long)s0 * QTILE + rr) * EMB);
    const floatx4* p1 = (const floatx4*)(part + ((long)s1 * QTILE + rr) * EMB);
    floatx4* po = (floatx4*)(out + (long)r * EMB);
    int c = threadIdx.x;                    // 128 threads x floatx4 = 512
    floatx4 v0 = p0[c], v1 = p1[c];
    po[c] = v0 * w0 + v1 * w1;
}

// --------------------------------------------------------------------------
extern "C" void kernel_launch(void* const* d_in, const int* in_sizes, int n_in,
                              void* d_out, int out_size, void* d_ws, size_t ws_size,
                              hipStream_t stream)
{
    const float* feat = (const float*)d_in[0];
    const void*  mask = d_in[1];
    const float* Wq   = (const float*)d_in[2];
    const float* Wk   = (const float*)d_in[3];
    const float* Wv   = (const float*)d_in[4];
    float* out = (float*)d_out;

    const long M  = (long)BQ * SEQ;
    const long NE = M * EMB;
    const long NW = (long)EMB * EMB;

    char* ws = (char*)d_ws;
    size_t off = 0;
    auto carve = [&](size_t bytes) -> void* {
        void* p = ws + off;
        off = (off + bytes + 4095) & ~(size_t)4095;
        return p;
    };
    bf16*   Xb   = (bf16*)carve(NE * 2);
    bf16*   Wqb  = (bf16*)carve(NW * 2);
    bf16*   Wkb  = (bf16*)carve(NW * 2);
    bf16*   Wvb  = (bf16*)carve(NW * 2);
    bf16*   Qb   = (bf16*)carve(NE * 2);
    bf16*   Kb   = (bf16*)carve(NE * 2);
    bf16*   Vt   = (bf16*)carve(NE * 2);
    float*  bias = (float*)carve(M * 4);
    float*  part = (float*)carve((long)256 * QTILE * EMB * 4);   // 64MB
    float2* ml   = (float2*)carve((long)256 * QTILE * 8);
    (void)ws_size; (void)in_sizes; (void)n_in; (void)out_size;

    const float qscale = 0.04419417382415922f;  // 512^-0.5 folded into Wq

    cvt_f32_to_bf16<<<dim3((NE / 4 + 255) / 256), dim3(256), 0, stream>>>(feat, Xb, NE / 4, 1.0f);
    cvt_f32_to_bf16<<<dim3((NW / 4 + 255) / 256), dim3(256), 0, stream>>>(Wq, Wqb, NW / 4, qscale);
    cvt_f32_to_bf16<<<dim3((NW / 4 + 255) / 256), dim3(256), 0, stream>>>(Wk, Wkb, NW / 4, 1.0f);
    cvt_f32_to_bf16<<<dim3((NW / 4 + 255) / 256), dim3(256), 0, stream>>>(Wv, Wvb, NW / 4, 1.0f);
    mask_to_bias<<<dim3(1), dim3(256), 0, stream>>>(mask, bias);

    gemm_bt<EPI_BF16><<<dim3(4, 128), dim3(256), 0, stream>>>(Xb, Wqb, Qb, EMB, EMB);
    gemm_bt<EPI_BF16><<<dim3(4, 128), dim3(256), 0, stream>>>(Xb, Wkb, Kb, EMB, EMB);
    gemm_bt<EPI_TRANS><<<dim3(4, 128), dim3(256), 0, stream>>>(Xb, Wvb, Vt, EMB, EMB);

    flash_attn<<<dim3(256), dim3(512), 0, stream>>>(Qb, Kb, Vt, bias, part, ml);
    combine_halves<<<dim3(BQ * SEQ), dim3(128), 0, stream>>>(part, ml, out);
}

// Round 6
// 217.806 us; speedup vs baseline: 2.8518x; 2.8518x over previous
//
#include <hip/hip_runtime.h>
#include <hip/hip_bf16.h>
#include <stdint.h>

#define BQ   8
#define SEQ  2048
#define EMB  512
#define KVB  32
#define HALF 1024   // keys per split-KV block
#define QTILE 128

typedef __attribute__((ext_vector_type(8))) short short8;
typedef __attribute__((ext_vector_type(4))) float floatx4;
typedef __attribute__((ext_vector_type(4))) unsigned short ushort4_t;
typedef __hip_bfloat16 bf16;

__device__ __forceinline__ unsigned short f2bf(float f) {
    union { bf16 h; unsigned short u; } c;
    c.h = __float2bfloat16(f);
    return c.u;
}

// ---------------- fp32 -> bf16 convert (optionally scaled) ----------------
__global__ __launch_bounds__(256) void cvt_f32_to_bf16(
    const float* __restrict__ in, bf16* __restrict__ out, long n4, float scale)
{
    long i = (long)blockIdx.x * 256 + threadIdx.x;
    if (i >= n4) return;
    floatx4 v = *(const floatx4*)(in + i * 4);
    ushort4_t o;
    o.x = f2bf(v.x * scale);
    o.y = f2bf(v.y * scale);
    o.z = f2bf(v.z * scale);
    o.w = f2bf(v.w * scale);
    *(ushort4_t*)((unsigned short*)out + i * 4) = o;
}

// ---------------- mask(bool, stored as int32 OR uint8) -> f32 bias --------
__global__ __launch_bounds__(256) void mask_to_bias(
    const void* __restrict__ mraw, float* __restrict__ bias)
{
    __shared__ int bad;
    int tid = threadIdx.x;
    if (tid == 0) bad = 0;
    __syncthreads();
    const int* mi = (const int*)mraw;
    int local = 0;
    for (int i = tid; i < 4096; i += 256) {
        unsigned v = (unsigned)mi[i];
        if (v > 1u) local = 1;
    }
    if (local) atomicOr(&bad, 1);
    __syncthreads();
    bool as_int = (bad == 0);
    const unsigned char* mb = (const unsigned char*)mraw;
    for (int i = tid; i < BQ * SEQ; i += 256) {
        int mv = as_int ? mi[i] : (int)mb[i];
        bias[i] = mv ? -1e9f : 0.0f;
    }
}

// ---------------- B^T GEMM: C[m][n] = sum_k A[m][k]*Bt[n][k] --------------
enum { EPI_BF16 = 0, EPI_TRANS = 1 };

template <int EPI>
__global__ __launch_bounds__(256) void gemm_bt(
    const bf16* __restrict__ A, const bf16* __restrict__ Bt,
    void* __restrict__ C, int Ncols, int K)
{
    __shared__ __attribute__((aligned(16))) bf16 lA[128 * 32];
    __shared__ __attribute__((aligned(16))) bf16 lB[128 * 32];

    const int tid  = threadIdx.x;
    const int lane = tid & 63;
    const int wv   = tid >> 6;
    const int wr   = wv >> 1, wc = wv & 1;
    const long brow = (long)blockIdx.y * 128;
    const long bcol = (long)blockIdx.x * 128;

    floatx4 acc[4][4];
#pragma unroll
    for (int m = 0; m < 4; m++)
#pragma unroll
        for (int n = 0; n < 4; n++) acc[m][n] = (floatx4)0.0f;

    const int hi  = lane >> 4;
    const int r16 = lane & 15;

    for (int kt = 0; kt < K; kt += 32) {
#pragma unroll
        for (int it = 0; it < 2; ++it) {
            int c = it * 256 + tid;
            const bf16* src = A + (brow + (c >> 2)) * (long)K + kt + (c & 3) * 8;
            __builtin_amdgcn_global_load_lds(
                (const __attribute__((address_space(1))) void*)src,
                (__attribute__((address_space(3))) void*)(&lA[(it * 256 + wv * 64) * 8]),
                16, 0, 0);
        }
#pragma unroll
        for (int it = 0; it < 2; ++it) {
            int c = it * 256 + tid;
            const bf16* src = Bt + (bcol + (c >> 2)) * (long)K + kt + (c & 3) * 8;
            __builtin_amdgcn_global_load_lds(
                (const __attribute__((address_space(1))) void*)src,
                (__attribute__((address_space(3))) void*)(&lB[(it * 256 + wv * 64) * 8]),
                16, 0, 0);
        }
        __syncthreads();

        short8 af[4], bfr[4];
#pragma unroll
        for (int m = 0; m < 4; m++)
            af[m] = *(const short8*)&lA[(wr * 64 + m * 16 + r16) * 32 + hi * 8];
#pragma unroll
        for (int n = 0; n < 4; n++)
            bfr[n] = *(const short8*)&lB[(wc * 64 + n * 16 + r16) * 32 + hi * 8];
#pragma unroll
        for (int m = 0; m < 4; m++)
#pragma unroll
            for (int n = 0; n < 4; n++)
                acc[m][n] = __builtin_amdgcn_mfma_f32_16x16x32_bf16(
                    af[m], bfr[n], acc[m][n], 0, 0, 0);
        __syncthreads();
    }

#pragma unroll
    for (int m = 0; m < 4; m++) {
#pragma unroll
        for (int n = 0; n < 4; n++) {
#pragma unroll
            for (int j = 0; j < 4; j++) {
                long row = brow + wr * 64 + m * 16 + hi * 4 + j;
                long col = bcol + wc * 64 + n * 16 + r16;
                float v = acc[m][n][j];
                if constexpr (EPI == EPI_BF16) {
                    ((bf16*)C)[row * (long)Ncols + col] = __float2bfloat16(v);
                } else {
                    // EPI_TRANS: Vt[b][e][key], keys permuted within each
                    // 32-block: pos = ((k>>2)&3)*8 + ((k>>4)&1)*4 + (k&3)
                    long bb = row >> 11;
                    int  t  = (int)(row & 2047);
                    int  t5 = t & 31;
                    int  tp = (t & ~31) | (((t5 >> 2) & 3) << 3)
                            | (((t5 >> 4) & 1) << 2) | (t5 & 3);
                    ((bf16*)C)[(bb * EMB + col) * SEQ + tp] = __float2bfloat16(v);
                }
            }
        }
    }
}

// ---------------- fused flash attention: 8 waves, swapped-S ---------------
// grid 256: bid&7=batch (XCD), (bid>>3)&15=qtile(128 rows), bid>>7=KV half.
// Wave w owns q-rows q0+w*16..+15 (all 512 e-cols). S^T = mfma(K,Q):
// lane(hi,r16) holds P[q=w*16+r16][keys {4hi+j, 16+4hi+j}] -> in-register
// softmax (2 shfl). PV: pa=[p0,p1] bf16; B-frag = ONE b128 from
// key-permuted Vlds (no repack). K,V double-buffered LDS; 1 barrier/tile.
__global__ __launch_bounds__(512) void flash_attn(
    const bf16* __restrict__ Q, const bf16* __restrict__ K,
    const bf16* __restrict__ Vtp, const float* __restrict__ bias,
    float* __restrict__ part, float2* __restrict__ ml)
{
    __shared__ __attribute__((aligned(16))) char smem[2 * 32768 + 2 * 32768 + HALF * 4];
    bf16* Klds0 = (bf16*)smem;                         // [2][32*512]
    bf16* Vlds0 = (bf16*)(smem + 65536);               // [2][512*32] permuted keys
    float* biasLds = (float*)(smem + 131072);          // [1024]

    const int tid  = threadIdx.x;
    const int lane = tid & 63;
    const int wv   = tid >> 6;          // 0..7
    const int r16  = lane & 15, hi = lane >> 4;

    const int bid = blockIdx.x;
    const int b   = bid & 7;            // batch -> XCD
    const int qt  = (bid >> 3) & 15;    // 0..15
    const int h   = bid >> 7;           // KV half
    const long q0  = (long)qt * QTILE;
    const long kv0 = (long)h * HALF;
    const int NT   = HALF / KVB;        // 32

    const bf16* Qb = Q   + (long)b * SEQ * EMB;
    const bf16* Kb = K   + (long)b * SEQ * EMB + kv0 * EMB;
    const bf16* Vb = Vtp + (long)b * EMB * SEQ;
    const float* biasb = bias + (long)b * SEQ + kv0;

    if (tid < HALF / 4)
        *(floatx4*)&biasLds[tid * 4] = *(const floatx4*)&biasb[tid * 4];

    // front-half Q fragments hoisted (ks 0..7); back half reloaded per tile
    const bf16* qrow = Qb + (q0 + wv * 16 + r16) * EMB;
    short8 qf[8];
#pragma unroll
    for (int ks = 0; ks < 8; ks++)
        qf[ks] = *(const short8*)(qrow + ks * 32 + hi * 8);

    floatx4 oacc[32];
#pragma unroll
    for (int nf = 0; nf < 32; nf++) oacc[nf] = (floatx4)0.f;

    float m_r = -3e38f, l_r = 0.f;

    // stage K tile (32x512, XOR-swz chunks) + V tile (512x32 permuted,
    // 16B-chunk rotation by col&3). 8 x global_load_lds per thread.
    auto stage = [&](int buf, int t) {
        bf16* kd = Klds0 + buf * (KVB * EMB);
        bf16* vd = Vlds0 + buf * (EMB * KVB);
#pragma unroll
        for (int i = 0; i < 4; i++) {
            int c = i * 512 + tid;          // K chunk id
            int row = c >> 6, cc = c & 63;
            const bf16* src = Kb + ((long)t * KVB + row) * EMB + ((cc ^ (row & 7)) << 3);
            __builtin_amdgcn_global_load_lds(
                (const __attribute__((address_space(1))) void*)src,
                (__attribute__((address_space(3))) void*)(kd + c * 8),
                16, 0, 0);
        }
#pragma unroll
        for (int i = 0; i < 4; i++) {
            int c = i * 512 + tid;          // V chunk id
            int col = c >> 2, ch = c & 3;
            const bf16* src = Vb + (long)col * SEQ + kv0 + t * KVB + ((ch ^ (col & 3)) << 3);
            __builtin_amdgcn_global_load_lds(
                (const __attribute__((address_space(1))) void*)src,
                (__attribute__((address_space(3))) void*)(vd + c * 8),
                16, 0, 0);
        }
    };

    stage(0, 0);
    __syncthreads();

    for (int t = 0; t < NT; t++) {
        const int cur = t & 1;
        if (t + 1 < NT) stage(cur ^ 1, t + 1);

        // back-half Q frags (L2-resident), issued early
        short8 qh[8];
#pragma unroll
        for (int i = 0; i < 8; i++)
            qh[i] = *(const short8*)(qrow + (8 + i) * 32 + hi * 8);

        // ---- S^T = mfma(A=K, B=Q): c0 keys 0..15, c1 keys 16..31 ----
        floatx4 c0 = (floatx4)0.f, c1 = (floatx4)0.f;
        const char* kbase = (const char*)(Klds0 + cur * (KVB * EMB));
        const int rowb0 = r16 * 1024, rowb1 = rowb0 + 16 * 1024;
        const int sw = r16 & 7;
        __builtin_amdgcn_s_setprio(1);
#pragma unroll
        for (int ks = 0; ks < 8; ks++) {
            const int cc = ((ks * 4 + hi) ^ sw) << 4;
            short8 k0 = *(const short8*)(kbase + rowb0 + cc);
            c0 = __builtin_amdgcn_mfma_f32_16x16x32_bf16(k0, qf[ks], c0, 0, 0, 0);
            short8 k1 = *(const short8*)(kbase + rowb1 + cc);
            c1 = __builtin_amdgcn_mfma_f32_16x16x32_bf16(k1, qf[ks], c1, 0, 0, 0);
        }
#pragma unroll
        for (int ks = 8; ks < 16; ks++) {
            const int cc = ((ks * 4 + hi) ^ sw) << 4;
            short8 k0 = *(const short8*)(kbase + rowb0 + cc);
            c0 = __builtin_amdgcn_mfma_f32_16x16x32_bf16(k0, qh[ks - 8], c0, 0, 0, 0);
            short8 k1 = *(const short8*)(kbase + rowb1 + cc);
            c1 = __builtin_amdgcn_mfma_f32_16x16x32_bf16(k1, qh[ks - 8], c1, 0, 0, 0);
        }
        __builtin_amdgcn_s_setprio(0);

        // ---- in-register online softmax (lane owns q-row r16) ----
        float s0[4], s1[4];
#pragma unroll
        for (int j = 0; j < 4; j++) {
            s0[j] = c0[j] + biasLds[t * KVB + hi * 4 + j];
            s1[j] = c1[j] + biasLds[t * KVB + 16 + hi * 4 + j];
        }
        float tmax = fmaxf(fmaxf(fmaxf(s0[0], s0[1]), fmaxf(s0[2], s0[3])),
                           fmaxf(fmaxf(s1[0], s1[1]), fmaxf(s1[2], s1[3])));
        tmax = fmaxf(tmax, __shfl_xor(tmax, 16));
        tmax = fmaxf(tmax, __shfl_xor(tmax, 32));

        float sc = 1.0f;
        int resc = 0;
        if (tmax > m_r + 8.0f) {                  // defer-max (T13)
            sc = __expf(m_r - tmax);
            m_r = tmax;
            resc = 1;
        }
        float p0[4], p1[4], rsum = 0.f;
#pragma unroll
        for (int j = 0; j < 4; j++) {
            p0[j] = __expf(s0[j] - m_r);
            p1[j] = __expf(s1[j] - m_r);
            rsum += p0[j] + p1[j];
        }
        rsum += __shfl_xor(rsum, 16);
        rsum += __shfl_xor(rsum, 32);
        l_r = l_r * sc + rsum;

        short8 pa;                                 // slots [p0, p1] match Vtp perm
#pragma unroll
        for (int j = 0; j < 4; j++) {
            pa[j]     = (short)f2bf(p0[j]);
            pa[4 + j] = (short)f2bf(p1[j]);
        }

        if (__any(resc)) {                         // rare O-rescale
#pragma unroll
            for (int j = 0; j < 4; j++) {
                float f = __shfl(sc, hi * 4 + j);
#pragma unroll
                for (int nf = 0; nf < 32; nf++) oacc[nf][j] *= f;
            }
        }

        // ---- O += P @ V: B-frag = one b128 from permuted Vlds ----
        const char* vbase = (const char*)(Vlds0 + cur * (EMB * KVB));
        __builtin_amdgcn_s_setprio(1);
#pragma unroll
        for (int cf = 0; cf < 32; cf++) {
            const int col = cf * 16 + r16;
            short8 vf = *(const short8*)(vbase + col * 64 + ((hi ^ (col & 3)) << 4));
            oacc[cf] = __builtin_amdgcn_mfma_f32_16x16x32_bf16(pa, vf, oacc[cf], 0, 0, 0);
        }
        __builtin_amdgcn_s_setprio(0);

        __syncthreads();   // staged t+1 drained; buffers swappable
    }

    // ---- epilogue: unnormalized O partial + (m,l) per q-row ----
    float* pb = part + (long)bid * QTILE * EMB;
#pragma unroll
    for (int j = 0; j < 4; j++) {
        long row = wv * 16 + hi * 4 + j;
#pragma unroll
        for (int cf = 0; cf < 32; cf++)
            pb[row * EMB + cf * 16 + r16] = oacc[cf][j];
    }
    if (hi == 0)
        ml[(long)bid * QTILE + wv * 16 + r16] = make_float2(m_r, l_r);
}

// ---------------- combine the two KV halves -------------------------------
__global__ __launch_bounds__(128) void combine_halves(
    const float* __restrict__ part, const float2* __restrict__ ml,
    float* __restrict__ out)
{
    const int r  = blockIdx.x;              // 0..16383 global q-row
    const int b  = r >> 11;
    const int rb = r & 2047;
    const int qt = rb >> 7;
    const int rr = rb & 127;
    const int s0 = qt * 8 + b;              // slot of half 0
    const int s1 = s0 + 128;

    float2 ml0 = ml[(long)s0 * QTILE + rr];
    float2 ml1 = ml[(long)s1 * QTILE + rr];
    float M  = fmaxf(ml0.x, ml1.x);
    float w0 = __expf(ml0.x - M), w1 = __expf(ml1.x - M);
    float inv = 1.0f / (w0 * ml0.y + w1 * ml1.y);
    w0 *= inv; w1 *= inv;

    const floatx4* p0 = (const floatx4*)(part + ((long)s0 * QTILE + rr) * EMB);
    const floatx4* p1 = (const floatx4*)(part + ((long)s1 * QTILE + rr) * EMB);
    floatx4* po = (floatx4*)(out + (long)r * EMB);
    int c = threadIdx.x;                    // 128 threads x floatx4 = 512
    floatx4 v0 = p0[c], v1 = p1[c];
    po[c] = v0 * w0 + v1 * w1;
}

// --------------------------------------------------------------------------
extern "C" void kernel_launch(void* const* d_in, const int* in_sizes, int n_in,
                              void* d_out, int out_size, void* d_ws, size_t ws_size,
                              hipStream_t stream)
{
    const float* feat = (const float*)d_in[0];
    const void*  mask = d_in[1];
    const float* Wq   = (const float*)d_in[2];
    const float* Wk   = (const float*)d_in[3];
    const float* Wv   = (const float*)d_in[4];
    float* out = (float*)d_out;

    const long M  = (long)BQ * SEQ;
    const long NE = M * EMB;
    const long NW = (long)EMB * EMB;

    char* ws = (char*)d_ws;
    size_t off = 0;
    auto carve = [&](size_t bytes) -> void* {
        void* p = ws + off;
        off = (off + bytes + 4095) & ~(size_t)4095;
        return p;
    };
    bf16*   Xb   = (bf16*)carve(NE * 2);
    bf16*   Wqb  = (bf16*)carve(NW * 2);
    bf16*   Wkb  = (bf16*)carve(NW * 2);
    bf16*   Wvb  = (bf16*)carve(NW * 2);
    bf16*   Qb   = (bf16*)carve(NE * 2);
    bf16*   Kb   = (bf16*)carve(NE * 2);
    bf16*   Vtp  = (bf16*)carve(NE * 2);
    float*  bias = (float*)carve(M * 4);
    float*  part = (float*)carve((long)256 * QTILE * EMB * 4);   // 64MB
    float2* ml   = (float2*)carve((long)256 * QTILE * 8);
    (void)ws_size; (void)in_sizes; (void)n_in; (void)out_size;

    const float qscale = 0.04419417382415922f;  // 512^-0.5 folded into Wq

    cvt_f32_to_bf16<<<dim3((NE / 4 + 255) / 256), dim3(256), 0, stream>>>(feat, Xb, NE / 4, 1.0f);
    cvt_f32_to_bf16<<<dim3((NW / 4 + 255) / 256), dim3(256), 0, stream>>>(Wq, Wqb, NW / 4, qscale);
    cvt_f32_to_bf16<<<dim3((NW / 4 + 255) / 256), dim3(256), 0, stream>>>(Wk, Wkb, NW / 4, 1.0f);
    cvt_f32_to_bf16<<<dim3((NW / 4 + 255) / 256), dim3(256), 0, stream>>>(Wv, Wvb, NW / 4, 1.0f);
    mask_to_bias<<<dim3(1), dim3(256), 0, stream>>>(mask, bias);

    gemm_bt<EPI_BF16><<<dim3(4, 128), dim3(256), 0, stream>>>(Xb, Wqb, Qb, EMB, EMB);
    gemm_bt<EPI_BF16><<<dim3(4, 128), dim3(256), 0, stream>>>(Xb, Wkb, Kb, EMB, EMB);
    gemm_bt<EPI_TRANS><<<dim3(4, 128), dim3(256), 0, stream>>>(Xb, Wvb, Vtp, EMB, EMB);

    flash_attn<<<dim3(256), dim3(512), 0, stream>>>(Qb, Kb, Vtp, bias, part, ml);
    combine_halves<<<dim3(BQ * SEQ), dim3(128), 0, stream>>>(part, ml, out);
}